// Round 2
// baseline (1011.572 us; speedup 1.0000x reference)
//
#include <hip/hip_runtime.h>
#include <stdint.h>

// Linformer attention, MI355X/gfx950.
// Pipeline: zero_ws -> proj_transpose(k),(v) -> project_kernel -> attn_kernel.
// All matmuls in fp16 MFMA (32x32x16), fp32 accumulate. Softmax in fp32.

typedef _Float16 half8  __attribute__((ext_vector_type(8)));
typedef _Float16 half4  __attribute__((ext_vector_type(4)));
typedef float  floatx16 __attribute__((ext_vector_type(16)));

static __device__ __forceinline__ uint32_t pk2(float a, float b) {
  union { _Float16 h[2]; uint32_t u; } un;
  un.h[0] = (_Float16)a; un.h[1] = (_Float16)b;   // RTN via v_cvt_f16_f32
  return un.u;
}

// 8 fp16 from LDS as two 8B reads (rows have odd-dword pitch -> only 8B aligned)
static __device__ __forceinline__ half8 lds_load8(const _Float16* p) {
  half4 lo = *(const half4*)p;
  half4 hi = *(const half4*)(p + 4);
  return __builtin_shufflevector(lo, hi, 0, 1, 2, 3, 4, 5, 6, 7);
}

// ---------------------------------------------------------------- zero ws ---
__global__ __launch_bounds__(256) void zero_ws_kernel(uint4* p, int n4) {
  int i = blockIdx.x * 256 + threadIdx.x;
  if (i < n4) p[i] = make_uint4(0u, 0u, 0u, 0u);
}

// -------------------------------------------- proj (S,K) f32 -> (K,S) fp16 --
__global__ __launch_bounds__(256) void proj_transpose(const float* __restrict__ src,
                                                      _Float16* __restrict__ dst) {
  // grid 256: 64 n-tiles x 4 kk-tiles of 64x64
  __shared__ float tile[64][65];
  const int n0 = (blockIdx.x >> 2) * 64;
  const int kk0 = (blockIdx.x & 3) * 64;
  const int t = threadIdx.x;
#pragma unroll
  for (int i = 0; i < 4; ++i) {
    int r = (t >> 4) + 16 * i;
    int c = 4 * (t & 15);
    float4 v = *(const float4*)(src + (size_t)(n0 + r) * 256 + kk0 + c);
    tile[r][c] = v.x; tile[r][c + 1] = v.y; tile[r][c + 2] = v.z; tile[r][c + 3] = v.w;
  }
  __syncthreads();
#pragma unroll
  for (int i = 0; i < 2; ++i) {
    int kk = (t >> 3) + 32 * i;
    int nb = 8 * (t & 7);
    half8 h;
#pragma unroll
    for (int j = 0; j < 8; ++j) h[j] = (_Float16)tile[nb + j][kk];
    *(half8*)(dst + (size_t)(kk0 + kk) * 4096 + n0 + nb) = h;
  }
}

// ------------------------------------------------- projection GEMM ----------
// C[kk][d] = sum_n projT[kk][n] * (kdat[n][d] * mask[n]),  per (bh, kind, S-half)
// grid 512: bid -> bh(128) x kind(2) x shalf(2). 256 thr = 4 waves.
// wave w owns kk in [64w, 64w+64): 2 M-tiles x 2 N-tiles of 32x32, acc 64 f32/lane.
#define PJ_PITCH 68   // fp16 elems/row: 34 dwords -> bank stride 2 (2-way = free)
__global__ __launch_bounds__(256, 2) void project_kernel(
    const float* __restrict__ kglob, const float* __restrict__ vglob,
    const _Float16* __restrict__ projTk, const _Float16* __restrict__ projTv,
    const float* __restrict__ mask,
    float* __restrict__ kpacc, float* __restrict__ vpacc) {
  const int bid = blockIdx.x;
  const int bh = bid >> 2;
  const int kind = (bid >> 1) & 1;
  const int shalf = bid & 1;
  const float* src = kind ? vglob : kglob;
  const _Float16* pt = kind ? projTv : projTk;
  float* outp = kind ? vpacc : kpacc;
  const int b = bh >> 4;  // H = 16
  const float* mrow = mask + (size_t)b * 4096 + shalf * 2048;
  src += (size_t)bh * 4096 * 64 + (size_t)shalf * 2048 * 64;
  pt += shalf * 2048;               // column offset inside [256][4096]
  outp += (size_t)bh * 256 * 64;

  __shared__ __align__(16) _Float16 lA[256 * PJ_PITCH];  // projT chunk [kk][n]
  __shared__ __align__(16) _Float16 lB[64 * PJ_PITCH];   // kdat chunk  [d][n] (transposed)

  const int t = threadIdx.x;
  const int wave = t >> 6, lane = t & 63, lh = lane >> 5, l31 = lane & 31;

  floatx16 acc[4];
#pragma unroll
  for (int i = 0; i < 4; ++i) acc[i] = (floatx16)0.0f;

  for (int ch = 0; ch < 32; ++ch) {
    const int n0 = ch * 64;
    // stage projT chunk: 256 rows x 64 n fp16. Each item: uint4 = 8 fp16.
    // 256 rows * 64 halfs / 8 halfs-per-item = 2048 items = 256 thr * 8 iters.
#pragma unroll
    for (int i = 0; i < 8; ++i) {
      int s = t + 256 * i;
      int kk = s >> 3, nb = (s & 7) * 8;
      uint4 v = *(const uint4*)(pt + (size_t)kk * 4096 + n0 + nb);
      uint2* dp = (uint2*)(lA + kk * PJ_PITCH + nb);
      dp[0] = make_uint2(v.x, v.y);
      dp[1] = make_uint2(v.z, v.w);
    }
    // stage kdat chunk masked + transposed to [d][n]; n-pairs packed -> b32 writes
#pragma unroll
    for (int i = 0; i < 2; ++i) {
      int s = t + 256 * i;
      int p = s >> 4, db = (s & 15) * 4;
      int n = n0 + 2 * p;
      float m0 = mrow[n], m1 = mrow[n + 1];
      float4 r0 = *(const float4*)(src + (size_t)n * 64 + db);
      float4 r1 = *(const float4*)(src + (size_t)(n + 1) * 64 + db);
      *(uint32_t*)(lB + (db + 0) * PJ_PITCH + 2 * p) = pk2(r0.x * m0, r1.x * m1);
      *(uint32_t*)(lB + (db + 1) * PJ_PITCH + 2 * p) = pk2(r0.y * m0, r1.y * m1);
      *(uint32_t*)(lB + (db + 2) * PJ_PITCH + 2 * p) = pk2(r0.z * m0, r1.z * m1);
      *(uint32_t*)(lB + (db + 3) * PJ_PITCH + 2 * p) = pk2(r0.w * m0, r1.w * m1);
    }
    __syncthreads();
#pragma unroll
    for (int kst = 0; kst < 4; ++kst) {
      const int noff = kst * 16 + 8 * lh;   // A/B: k = 8*(lane>>5)+j
      half8 bfr[2], afr[2];
#pragma unroll
      for (int nt = 0; nt < 2; ++nt)
        bfr[nt] = lds_load8(lB + (nt * 32 + l31) * PJ_PITCH + noff);
#pragma unroll
      for (int mt = 0; mt < 2; ++mt)
        afr[mt] = lds_load8(lA + (wave * 64 + mt * 32 + l31) * PJ_PITCH + noff);
#pragma unroll
      for (int mt = 0; mt < 2; ++mt)
#pragma unroll
        for (int nt = 0; nt < 2; ++nt)
          acc[2 * mt + nt] =
              __builtin_amdgcn_mfma_f32_32x32x16_f16(afr[mt], bfr[nt], acc[2 * mt + nt], 0, 0, 0);
    }
    __syncthreads();
  }
  // C/D layout: col=lane&31, row=(r&3)+8*(r>>2)+4*(lane>>5)
#pragma unroll
  for (int mt = 0; mt < 2; ++mt)
#pragma unroll
    for (int nt = 0; nt < 2; ++nt)
#pragma unroll
      for (int r = 0; r < 16; ++r) {
        int kk = wave * 64 + mt * 32 + (r & 3) + 8 * (r >> 2) + 4 * lh;
        int d = nt * 32 + l31;
        unsafeAtomicAdd(outp + kk * 64 + d, acc[2 * mt + nt][r]);
      }
}

// ------------------------------------------------- attention kernel ---------
// grid 4096: bh(128) x qtile(32 of 128 rows). 256 thr = 4 waves; wave w owns
// q-rows [32w,32w+32). Computes S^T = kp @ q^T (so softmax axis is in-lane),
// softmax in fp32 regs, attn written f32 from regs, PV via xor-32 shuffle of P
// (C layout col==B layout col) against v_proj^T staged in LDS.
#define VP_PITCH 260  // 130 dwords -> bank stride 2, rows 8B aligned
__global__ __launch_bounds__(256, 2) void attn_kernel(
    const float* __restrict__ q, const float* __restrict__ kp,
    const float* __restrict__ vp, float* __restrict__ out,
    float* __restrict__ attnp) {
  const int bid = blockIdx.x;
  const int bh = bid >> 5, qt = bid & 31;
  const int q0 = qt * 128;
  q += (size_t)bh * 4096 * 64 + (size_t)q0 * 64;
  kp += (size_t)bh * 256 * 64;
  vp += (size_t)bh * 256 * 64;
  out += (size_t)bh * 4096 * 64 + (size_t)q0 * 64;
  attnp += (size_t)bh * 4096 * 256 + (size_t)q0 * 256;

  __shared__ __align__(16) _Float16 smem[(256 + 128) * PJ_PITCH];  // 52224 B
  _Float16* lkp = smem;                   // [256][68] fp16
  _Float16* lq = smem + 256 * PJ_PITCH;   // [128][68] fp16 (q * 0.125)
  _Float16* lvp = smem;                   // [64][260] fp16, overlays lkp after scores

  const int t = threadIdx.x;
  const int wave = t >> 6, lane = t & 63, lh = lane >> 5, l31 = lane & 31;

  // ---- stage kp (256x64) and q (128x64, scaled by 1/sqrt(D)=0.125) ----
#pragma unroll
  for (int i = 0; i < 16; ++i) {
    int s = t + 256 * i;
    int row = s >> 4, db = (s & 15) * 4;
    float4 v = *(const float4*)(kp + (size_t)row * 64 + db);
    uint32_t* dp = (uint32_t*)(lkp + row * PJ_PITCH + db);
    dp[0] = pk2(v.x, v.y);
    dp[1] = pk2(v.z, v.w);
  }
#pragma unroll
  for (int i = 0; i < 8; ++i) {
    int s = t + 256 * i;
    int row = s >> 4, db = (s & 15) * 4;
    float4 v = *(const float4*)(q + (size_t)row * 64 + db);
    uint32_t* dp = (uint32_t*)(lq + row * PJ_PITCH + db);
    dp[0] = pk2(v.x * 0.125f, v.y * 0.125f);
    dp[1] = pk2(v.z * 0.125f, v.w * 0.125f);
  }
  __syncthreads();

  // ---- scores: S^T[kk][qrow] = kp @ (q*scale)^T ; M=256 kk, N=32 qrow/wave, K=64
  const int qrow = wave * 32 + l31;  // this lane's q-row (B/C col = lane&31)
  half8 qf[4];
#pragma unroll
  for (int kst = 0; kst < 4; ++kst)
    qf[kst] = lds_load8(lq + qrow * PJ_PITCH + kst * 16 + 8 * lh);

  floatx16 sc[8];
#pragma unroll
  for (int i = 0; i < 8; ++i) sc[i] = (floatx16)0.0f;
#pragma unroll
  for (int mt = 0; mt < 8; ++mt)
#pragma unroll
    for (int kst = 0; kst < 4; ++kst) {
      half8 af = lds_load8(lkp + (mt * 32 + l31) * PJ_PITCH + kst * 16 + 8 * lh);
      sc[mt] = __builtin_amdgcn_mfma_f32_32x32x16_f16(af, qf[kst], sc[mt], 0, 0, 0);
    }
  __syncthreads();  // all waves done with lkp -> safe to overlay with vp

  // ---- stage v_proj transposed [d][kk] into dead kp region ----
#pragma unroll
  for (int i = 0; i < 16; ++i) {
    int kk = 2 * ((t >> 5) + 8 * i);
    int d0 = 2 * (t & 31);
    float2 a = *(const float2*)(vp + (size_t)kk * 64 + d0);
    float2 b = *(const float2*)(vp + (size_t)(kk + 1) * 64 + d0);
    *(uint32_t*)(lvp + (d0 + 0) * VP_PITCH + kk) = pk2(a.x, b.x);
    *(uint32_t*)(lvp + (d0 + 1) * VP_PITCH + kk) = pk2(a.y, b.y);
  }

  // ---- softmax over kk: lane holds 128 of 256 kk for its q-row; partner
  //      (lane^32) holds the complement.
  float mx = -3.0e38f;
#pragma unroll
  for (int i = 0; i < 8; ++i)
#pragma unroll
    for (int r = 0; r < 16; ++r) mx = fmaxf(mx, sc[i][r]);
  mx = fmaxf(mx, __shfl_xor(mx, 32, 64));
  float sum = 0.0f;
#pragma unroll
  for (int i = 0; i < 8; ++i)
#pragma unroll
    for (int r = 0; r < 16; ++r) {
      float pe = __expf(sc[i][r] - mx);
      sc[i][r] = pe;
      sum += pe;
    }
  sum += __shfl_xor(sum, 32, 64);
  const float inv = 1.0f / sum;
#pragma unroll
  for (int i = 0; i < 8; ++i)
#pragma unroll
    for (int r = 0; r < 16; ++r) sc[i][r] *= inv;

  // ---- write attn probs (f32, from C-layout quads: 4 consecutive kk each) ----
  {
    float* arow = attnp + (size_t)qrow * 256;
#pragma unroll
    for (int mt = 0; mt < 8; ++mt)
#pragma unroll
      for (int g = 0; g < 4; ++g) {
        int kkb = mt * 32 + 8 * g + 4 * lh;
        float4 v;
        v.x = sc[mt][4 * g + 0]; v.y = sc[mt][4 * g + 1];
        v.z = sc[mt][4 * g + 2]; v.w = sc[mt][4 * g + 3];
        *(float4*)(arow + kkb) = v;
      }
  }
  __syncthreads();  // vp staged & everyone past lkp reads

  // ---- PV: O^T[d][qrow] = vp^T @ P^T ; A = vp^T from LDS, B = P^T from regs.
  // B-frag for kstep s (kk in [16s,16s+16)): tile=s>>1, h2=s&1.
  // frag[j<4] = lh0-holder's reg (4*(2*h2+self_lh)+i), frag[j>=4] = lh1-holder's.
  floatx16 ob[2];
  ob[0] = (floatx16)0.0f;
  ob[1] = (floatx16)0.0f;
#pragma unroll
  for (int s = 0; s < 16; ++s) {
    const int tile = s >> 1, h2 = s & 1;
    half8 bf;
#pragma unroll
    for (int i = 0; i < 4; ++i) {
      float own = lh ? sc[tile][8 * h2 + 4 + i] : sc[tile][8 * h2 + i];
      float send = lh ? sc[tile][8 * h2 + i] : sc[tile][8 * h2 + 4 + i];
      float recv = __shfl_xor(send, 32, 64);
      float j0 = lh ? recv : own;   // from lane-half-0 holder
      float j4 = lh ? own : recv;   // from lane-half-1 holder
      bf[i] = (_Float16)j0;
      bf[4 + i] = (_Float16)j4;
    }
#pragma unroll
    for (int mo = 0; mo < 2; ++mo) {
      half8 af = lds_load8(lvp + (mo * 32 + l31) * VP_PITCH + s * 16 + 8 * lh);
      ob[mo] = __builtin_amdgcn_mfma_f32_32x32x16_f16(af, bf, ob[mo], 0, 0, 0);
    }
  }

  // ---- write out (f32): C col = qrow, rows = d quads ----
  {
    float* orow = out + (size_t)qrow * 64;
#pragma unroll
    for (int mo = 0; mo < 2; ++mo)
#pragma unroll
      for (int g = 0; g < 4; ++g) {
        int d = mo * 32 + 8 * g + 4 * lh;
        float4 v;
        v.x = ob[mo][4 * g + 0]; v.y = ob[mo][4 * g + 1];
        v.z = ob[mo][4 * g + 2]; v.w = ob[mo][4 * g + 3];
        *(float4*)(orow + d) = v;
      }
  }
}

// ---------------------------------------------------------------- launch ----
extern "C" void kernel_launch(void* const* d_in, const int* in_sizes, int n_in,
                              void* d_out, int out_size, void* d_ws, size_t ws_size,
                              hipStream_t stream) {
  const float* qin = (const float*)d_in[0];
  const float* kin = (const float*)d_in[1];
  const float* vin = (const float*)d_in[2];
  const float* mask = (const float*)d_in[3];
  const float* pjk = (const float*)d_in[4];
  const float* pjv = (const float*)d_in[5];
  float* out0 = (float*)d_out;
  float* attn = out0 + (size_t)8 * 16 * 4096 * 64;  // out first, then attn_probs

  char* ws = (char*)d_ws;
  float* kpacc = (float*)ws;                          // [128][256][64] f32, 8 MB
  float* vpacc = (float*)(ws + 8388608);              // [128][256][64] f32, 8 MB
  _Float16* ptk = (_Float16*)(ws + 16777216);         // [256][4096] fp16, 2 MB
  _Float16* ptv = (_Float16*)(ws + 16777216 + 2097152);

  // zero the fp32 atomic accumulators (ws is poisoned each launch)
  zero_ws_kernel<<<4096, 256, 0, stream>>>((uint4*)ws, 16777216 / 16);
  proj_transpose<<<256, 256, 0, stream>>>(pjk, ptk);
  proj_transpose<<<256, 256, 0, stream>>>(pjv, ptv);
  project_kernel<<<512, 256, 0, stream>>>(kin, vin, ptk, ptv, mask, kpacc, vpacc);
  attn_kernel<<<4096, 256, 0, stream>>>(qin, kpacc, vpacc, out0, attn);
}